// Round 2
// baseline (9657.998 us; speedup 1.0000x reference)
//
#include <hip/hip_runtime.h>

typedef _Float16 half2v __attribute__((ext_vector_type(2)));
typedef _Float16 half8v __attribute__((ext_vector_type(8)));
typedef float f32x4 __attribute__((ext_vector_type(4)));

#define S_LEN 2048

static __device__ __forceinline__ unsigned int pk16(float a, float b) {
  half2v h; h[0] = (_Float16)a; h[1] = (_Float16)b;
  return __builtin_bit_cast(unsigned int, h);
}
static __device__ __forceinline__ float uph(unsigned short u) {
  return (float)__builtin_bit_cast(_Float16, u);
}
static __device__ __forceinline__ unsigned short f16bits(float x) {
  return __builtin_bit_cast(unsigned short, (_Float16)x);
}
static __device__ __forceinline__ float dot2a(unsigned int h2, unsigned int w2, float acc) {
  return __builtin_amdgcn_fdot2(__builtin_bit_cast(half2v, h2),
                                __builtin_bit_cast(half2v, w2), acc, false);
}
static __device__ __forceinline__ float sigm(float x) {
  return 1.0f / (1.0f + __expf(-x));
}
static __device__ __forceinline__ float tanh_fast(float x) {
  float e = __expf(2.0f * x);
  return 1.0f - 2.0f / (e + 1.0f);   // safe at +/-inf
}

// ---------------------------------------------------------------------------
// Kernel 1: P[m, g*256+j] = f16( x[m,:] . W{g}_x[j,:] + b{g}[j] )
// m = s*64+b in [0,131072), tiles 128x128, BK=64, fp16 MFMA. (unchanged, R1)
// ---------------------------------------------------------------------------
__global__ __launch_bounds__(256, 2) void gemm_pre(
    const float* __restrict__ x,
    const float* __restrict__ Wz, const float* __restrict__ bz,
    const float* __restrict__ Wr, const float* __restrict__ br,
    const float* __restrict__ Wc, const float* __restrict__ bc,
    const float* __restrict__ Wh, const float* __restrict__ bh,
    unsigned short* __restrict__ P)
{
  __shared__ __align__(16) char As[128 * 128];
  __shared__ __align__(16) char Bs[128 * 128];
  const int t = threadIdx.x;
  const int lane = t & 63;
  const int wid = t >> 6;
  const int wm = wid >> 1, wn = wid & 1;
  const int n0 = blockIdx.x * 128;
  const int m0 = blockIdx.y * 128;

  f32x4 acc[4][4];
  #pragma unroll
  for (int i = 0; i < 4; ++i)
    #pragma unroll
    for (int jq = 0; jq < 4; ++jq) acc[i][jq] = f32x4{0.f, 0.f, 0.f, 0.f};

  for (int kk = 0; kk < 4; ++kk) {
    __syncthreads();
    #pragma unroll
    for (int it = 0; it < 8; ++it) {
      int fl = it * 256 + t;
      int row = fl >> 4;
      int c4 = fl & 15;
      f32x4 v = *(const f32x4*)(x + (size_t)(m0 + row) * 256 + kk * 64 + c4 * 4);
      uint2 pw; pw.x = pk16(v[0], v[1]); pw.y = pk16(v[2], v[3]);
      *(uint2*)(As + row * 128 + ((c4 * 8) ^ ((row & 7) << 4))) = pw;

      int n = n0 + row;
      int g = n >> 8; int jc = n & 255;
      const float* W = (g == 0) ? Wz : (g == 1) ? Wr : (g == 2) ? Wc : Wh;
      f32x4 wv = *(const f32x4*)(W + jc * 512 + kk * 64 + c4 * 4);
      uint2 qw; qw.x = pk16(wv[0], wv[1]); qw.y = pk16(wv[2], wv[3]);
      *(uint2*)(Bs + row * 128 + ((c4 * 8) ^ ((row & 7) << 4))) = qw;
    }
    __syncthreads();
    #pragma unroll
    for (int k2 = 0; k2 < 2; ++k2) {
      const int kb = k2 * 64 + (lane >> 4) * 16;
      half8v a[4], bfr[4];
      #pragma unroll
      for (int i = 0; i < 4; ++i) {
        int ar = wm * 64 + i * 16 + (lane & 15);
        a[i] = *(const half8v*)(As + ar * 128 + (kb ^ ((ar & 7) << 4)));
        int br2 = wn * 64 + i * 16 + (lane & 15);
        bfr[i] = *(const half8v*)(Bs + br2 * 128 + (kb ^ ((br2 & 7) << 4)));
      }
      #pragma unroll
      for (int i = 0; i < 4; ++i)
        #pragma unroll
        for (int jq = 0; jq < 4; ++jq)
          acc[i][jq] = __builtin_amdgcn_mfma_f32_16x16x32_f16(a[i], bfr[jq], acc[i][jq], 0, 0, 0);
    }
  }
  #pragma unroll
  for (int jq = 0; jq < 4; ++jq) {
    int col = n0 + wn * 64 + jq * 16 + (lane & 15);
    int g = col >> 8; int jc = col & 255;
    const float* bp = (g == 0) ? bz : (g == 1) ? br : (g == 2) ? bc : bh;
    float bias = bp[jc];
    #pragma unroll
    for (int i = 0; i < 4; ++i) {
      int rowb = m0 + wm * 64 + i * 16 + (lane >> 4) * 4;
      #pragma unroll
      for (int r = 0; r < 4; ++r) {
        float vv = acc[i][jq][r] + bias;
        P[(size_t)(rowb + r) * 1024 + col] = f16bits(vv);
      }
    }
  }
}

// ---------------------------------------------------------------------------
// Kernel 2: persistent scan, sliced-partial design.
// 64 blocks x 512 threads. Lane l: slice s8=l>>3 (32 h-elems), q8=l&7.
// Phase A: 12 rows (z,r,g) x 32-elem partial dots from reg weights, shfl
//          reduce, write pre[768].
// Phase C: 4 rows (c) x 32-elem partials, Wc streamed from rotated LDS.
// h/rh distributed via 8x80B padded LDS (conflict-free broadcast reads).
// ---------------------------------------------------------------------------
__global__ __launch_bounds__(512, 2) void gru_scan(
    const float* __restrict__ Wz, const float* __restrict__ Wr,
    const float* __restrict__ Wc, const float* __restrict__ Wh,
    const float* __restrict__ gamma, const float* __restrict__ beta,
    const unsigned short* __restrict__ P,
    float* __restrict__ out)
{
  __shared__ __align__(16) unsigned char wc_lds[256 * 512];  // Wc f16, rotated
  __shared__ __align__(16) unsigned char hpad[640];          // h f16: slice s at s*80
  __shared__ __align__(16) unsigned char rhpad[640];         // rh f16 same layout
  __shared__ float pre[768];   // z[0,256) r[256,512) g then c reuse [512,768)
  __shared__ float2 red[4];

  const int t = threadIdx.x;
  const int b = blockIdx.x;
  const int w = t >> 6;
  const int l = t & 63;
  const int s8 = l >> 3;
  const int q8 = l & 7;
  const int j = t & 255;

  // ---- stage Wc -> LDS as f16, rotation-swizzled: off' = (off + (row&31)*16) & 511
  #pragma unroll
  for (int it = 0; it < 16; ++it) {
    int f = it * 512 + t;
    int rho = f >> 5;
    int slot = f & 31;
    const float* src = Wc + rho * 512 + 256 + slot * 8;
    f32x4 v0 = *(const f32x4*)(src);
    f32x4 v1 = *(const f32x4*)(src + 4);
    uint4 pw;
    pw.x = pk16(v0[0], v0[1]); pw.y = pk16(v0[2], v0[3]);
    pw.z = pk16(v1[0], v1[1]); pw.w = pk16(v1[2], v1[3]);
    int off = (slot * 16 + ((rho & 31) << 4)) & 511;
    *(uint4*)(wc_lds + rho * 512 + off) = pw;
  }

  // ---- A-gate weights (z,r,g) in registers: 12 rows x 32 f16 = 192 VGPRs
  unsigned int wA[12][16];
  #pragma unroll
  for (int i = 0; i < 12; ++i) {
    int rho = 96 * w + 8 * i + q8;
    const float* Wp = (rho < 256) ? Wz : (rho < 512) ? Wr : Wh;
    const float* src = Wp + (rho & 255) * 512 + 256 + s8 * 32;
    #pragma unroll
    for (int m = 0; m < 8; ++m) {
      f32x4 v = *(const f32x4*)(src + m * 4);
      wA[i][2 * m]     = pk16(v[0], v[1]);
      wA[i][2 * m + 1] = pk16(v[2], v[3]);
    }
  }

  if (t < 160) { ((unsigned int*)hpad)[t] = 0u; ((unsigned int*)rhpad)[t] = 0u; }

  float h_own = 0.f, gam = 0.f, bet = 0.f;
  if (t < 256) { gam = gamma[j]; bet = beta[j]; }
  unsigned short czx = 0, crx = 0, ccx = 0, cgx = 0;
  if (t < 256) {
    const unsigned short* pb = P + (size_t)b * 1024;
    czx = pb[j]; crx = pb[256 + j]; ccx = pb[512 + j]; cgx = pb[768 + j];
  }
  __syncthreads();

  float zval = 0.f, gval = 0.f;
  #pragma unroll 1
  for (int s = 0; s < S_LEN; ++s) {
    unsigned short nzx = 0, nrx = 0, ncx = 0, ngx = 0;
    if (t < 256 && s + 1 < S_LEN) {
      const unsigned short* pb = P + ((size_t)(s + 1) * 64 + b) * 1024;
      nzx = pb[j]; nrx = pb[256 + j]; ncx = pb[512 + j]; ngx = pb[768 + j];
    }
    // ---- Phase A: z,r,g partial dots over own 32-elem h slice
    unsigned int hh[16];
    #pragma unroll
    for (int u = 0; u < 4; ++u) {
      uint4 hv = *(const uint4*)(hpad + s8 * 80 + u * 16);
      hh[4*u] = hv.x; hh[4*u+1] = hv.y; hh[4*u+2] = hv.z; hh[4*u+3] = hv.w;
    }
    float acc[12];
    #pragma unroll
    for (int i = 0; i < 12; ++i) {
      float a = 0.f;
      #pragma unroll
      for (int v = 0; v < 16; ++v) a = dot2a(hh[v], wA[i][v], a);
      a += __shfl_xor(a, 8);
      a += __shfl_xor(a, 16);
      a += __shfl_xor(a, 32);
      acc[i] = a;
    }
    {
      float v1s = (s8==0)?acc[0]:(s8==1)?acc[1]:(s8==2)?acc[2]:(s8==3)?acc[3]:
                  (s8==4)?acc[4]:(s8==5)?acc[5]:(s8==6)?acc[6]:acc[7];
      pre[96 * w + l] = v1s;
      if (l < 32) {
        int i2 = l >> 3;
        float v2s = (i2==0)?acc[8]:(i2==1)?acc[9]:(i2==2)?acc[10]:acc[11];
        pre[96 * w + 64 + l] = v2s;
      }
    }
    __syncthreads();                                   // (1)
    // ---- Phase B: gates z,r,g; distribute rh
    if (t < 256) {
      zval = sigm(pre[j] + uph(czx));
      float rr = sigm(pre[256 + j] + uph(crx));
      gval = sigm(pre[512 + j] + uph(cgx));
      float rh = rr * h_own;
      *(unsigned short*)(rhpad + (j >> 5) * 80 + (j & 31) * 2) = f16bits(rh);
    }
    __syncthreads();                                   // (2)
    // ---- Phase C: c partial dots, Wc from rotated LDS
    unsigned int rr16[16];
    #pragma unroll
    for (int u = 0; u < 4; ++u) {
      uint4 hv = *(const uint4*)(rhpad + s8 * 80 + u * 16);
      rr16[4*u] = hv.x; rr16[4*u+1] = hv.y; rr16[4*u+2] = hv.z; rr16[4*u+3] = hv.w;
    }
    float accC[4];
    #pragma unroll
    for (int i = 0; i < 4; ++i) {
      int rho = 32 * w + 8 * i + q8;
      const unsigned char* base = wc_lds + rho * 512;
      int r5x = (rho & 31) << 4;
      float a = 0.f;
      #pragma unroll
      for (int u = 0; u < 4; ++u) {
        uint4 wv = *(const uint4*)(base + ((s8 * 64 + u * 16 + r5x) & 511));
        a = dot2a(rr16[4*u+0], wv.x, a);
        a = dot2a(rr16[4*u+1], wv.y, a);
        a = dot2a(rr16[4*u+2], wv.z, a);
        a = dot2a(rr16[4*u+3], wv.w, a);
      }
      a += __shfl_xor(a, 8);
      a += __shfl_xor(a, 16);
      a += __shfl_xor(a, 32);
      accC[i] = a;
    }
    if (l < 32) {
      int i2 = l >> 3;
      float vcs = (i2==0)?accC[0]:(i2==1)?accC[1]:(i2==2)?accC[2]:accC[3];
      pre[512 + 32 * w + l] = vcs;
    }
    __syncthreads();                                   // (3)
    // ---- Phase D: combine + highway + LN
    float hfin = 0.f;
    if (t < 256) {
      float ht = tanh_fast(pre[512 + j] + uph(ccx));
      float hn = (1.f - zval) * h_own + zval * ht;
      hfin = gval * hn + (1.f - gval) * h_own;
      h_own = hn;
      *(unsigned short*)(hpad + (j >> 5) * 80 + (j & 31) * 2) = f16bits(hn);
      float s1 = hfin, s2 = hfin * hfin;
      #pragma unroll
      for (int off = 1; off < 64; off <<= 1) {
        s1 += __shfl_xor(s1, off);
        s2 += __shfl_xor(s2, off);
      }
      if ((t & 63) == 0) red[t >> 6] = make_float2(s1, s2);
    }
    __syncthreads();                                   // (4)
    if (t < 256) {
      float S1 = red[0].x + red[1].x + red[2].x + red[3].x;
      float S2 = red[0].y + red[1].y + red[2].y + red[3].y;
      float mu = S1 * (1.0f / 256.0f);
      float var = S2 * (1.0f / 256.0f) - mu * mu;
      float rs = rsqrtf(var + 1e-5f);
      out[(size_t)s * 16384 + b * 256 + j] = (hfin - mu) * rs * gam + bet;
    }
    czx = nzx; crx = nrx; ccx = ncx; cgx = ngx;
  }
  if (t < 256) out[(size_t)33554432 + b * 256 + j] = h_own;
}

extern "C" void kernel_launch(void* const* d_in, const int* in_sizes, int n_in,
                              void* d_out, int out_size, void* d_ws, size_t ws_size,
                              hipStream_t stream) {
  const float* x  = (const float*)d_in[0];
  const float* Wz = (const float*)d_in[1];
  const float* bz = (const float*)d_in[2];
  const float* Wr = (const float*)d_in[3];
  const float* br = (const float*)d_in[4];
  const float* Wc = (const float*)d_in[5];
  const float* bc = (const float*)d_in[6];
  const float* Wh = (const float*)d_in[7];
  const float* bh = (const float*)d_in[8];
  const float* gamma = (const float*)d_in[9];
  const float* beta  = (const float*)d_in[10];
  unsigned short* P = (unsigned short*)d_ws;   // 131072 x 1024 f16 = 256 MB
  float* out = (float*)d_out;

  dim3 g1(8, 1024);
  gemm_pre<<<g1, 256, 0, stream>>>(x, Wz, bz, Wr, br, Wc, bc, Wh, bh, P);
  gru_scan<<<64, 512, 0, stream>>>(Wz, Wr, Wc, Wh, gamma, beta, P, out);
}

// Round 3
// 9648.907 us; speedup vs baseline: 1.0009x; 1.0009x over previous
//
#include <hip/hip_runtime.h>

typedef _Float16 half2v __attribute__((ext_vector_type(2)));
typedef _Float16 half8v __attribute__((ext_vector_type(8)));
typedef float f32x4 __attribute__((ext_vector_type(4)));

#define S_LEN 2048

static __device__ __forceinline__ unsigned int pk16(float a, float b) {
  half2v h; h[0] = (_Float16)a; h[1] = (_Float16)b;
  return __builtin_bit_cast(unsigned int, h);
}
static __device__ __forceinline__ float uph(unsigned short u) {
  return (float)__builtin_bit_cast(_Float16, u);
}
static __device__ __forceinline__ unsigned short f16bits(float x) {
  return __builtin_bit_cast(unsigned short, (_Float16)x);
}
static __device__ __forceinline__ float dot2a(unsigned int h2, unsigned int w2, float acc) {
  return __builtin_amdgcn_fdot2(__builtin_bit_cast(half2v, h2),
                                __builtin_bit_cast(half2v, w2), acc, false);
}
static __device__ __forceinline__ float sigm(float x) {
  return 1.0f / (1.0f + __expf(-x));
}
static __device__ __forceinline__ float tanh_fast(float x) {
  float e = __expf(2.0f * x);
  return 1.0f - 2.0f / (e + 1.0f);   // safe at +/-inf
}

// ---------------------------------------------------------------------------
// Kernel 1: P[m, g*256+j] = f16( x[m,:] . W{g}_x[j,:] + b{g}[j] )
// m = s*64+b in [0,131072), tiles 128x128, BK=64, fp16 MFMA. (unchanged)
// ---------------------------------------------------------------------------
__global__ __launch_bounds__(256, 2) void gemm_pre(
    const float* __restrict__ x,
    const float* __restrict__ Wz, const float* __restrict__ bz,
    const float* __restrict__ Wr, const float* __restrict__ br,
    const float* __restrict__ Wc, const float* __restrict__ bc,
    const float* __restrict__ Wh, const float* __restrict__ bh,
    unsigned short* __restrict__ P)
{
  __shared__ __align__(16) char As[128 * 128];
  __shared__ __align__(16) char Bs[128 * 128];
  const int t = threadIdx.x;
  const int lane = t & 63;
  const int wid = t >> 6;
  const int wm = wid >> 1, wn = wid & 1;
  const int n0 = blockIdx.x * 128;
  const int m0 = blockIdx.y * 128;

  f32x4 acc[4][4];
  #pragma unroll
  for (int i = 0; i < 4; ++i)
    #pragma unroll
    for (int jq = 0; jq < 4; ++jq) acc[i][jq] = f32x4{0.f, 0.f, 0.f, 0.f};

  for (int kk = 0; kk < 4; ++kk) {
    __syncthreads();
    #pragma unroll
    for (int it = 0; it < 8; ++it) {
      int fl = it * 256 + t;
      int row = fl >> 4;
      int c4 = fl & 15;
      f32x4 v = *(const f32x4*)(x + (size_t)(m0 + row) * 256 + kk * 64 + c4 * 4);
      uint2 pw; pw.x = pk16(v[0], v[1]); pw.y = pk16(v[2], v[3]);
      *(uint2*)(As + row * 128 + ((c4 * 8) ^ ((row & 7) << 4))) = pw;

      int n = n0 + row;
      int g = n >> 8; int jc = n & 255;
      const float* W = (g == 0) ? Wz : (g == 1) ? Wr : (g == 2) ? Wc : Wh;
      f32x4 wv = *(const f32x4*)(W + jc * 512 + kk * 64 + c4 * 4);
      uint2 qw; qw.x = pk16(wv[0], wv[1]); qw.y = pk16(wv[2], wv[3]);
      *(uint2*)(Bs + row * 128 + ((c4 * 8) ^ ((row & 7) << 4))) = qw;
    }
    __syncthreads();
    #pragma unroll
    for (int k2 = 0; k2 < 2; ++k2) {
      const int kb = k2 * 64 + (lane >> 4) * 16;
      half8v a[4], bfr[4];
      #pragma unroll
      for (int i = 0; i < 4; ++i) {
        int ar = wm * 64 + i * 16 + (lane & 15);
        a[i] = *(const half8v*)(As + ar * 128 + (kb ^ ((ar & 7) << 4)));
        int br2 = wn * 64 + i * 16 + (lane & 15);
        bfr[i] = *(const half8v*)(Bs + br2 * 128 + (kb ^ ((br2 & 7) << 4)));
      }
      #pragma unroll
      for (int i = 0; i < 4; ++i)
        #pragma unroll
        for (int jq = 0; jq < 4; ++jq)
          acc[i][jq] = __builtin_amdgcn_mfma_f32_16x16x32_f16(a[i], bfr[jq], acc[i][jq], 0, 0, 0);
    }
  }
  #pragma unroll
  for (int jq = 0; jq < 4; ++jq) {
    int col = n0 + wn * 64 + jq * 16 + (lane & 15);
    int g = col >> 8; int jc = col & 255;
    const float* bp = (g == 0) ? bz : (g == 1) ? br : (g == 2) ? bc : bh;
    float bias = bp[jc];
    #pragma unroll
    for (int i = 0; i < 4; ++i) {
      int rowb = m0 + wm * 64 + i * 16 + (lane >> 4) * 4;
      #pragma unroll
      for (int r = 0; r < 4; ++r) {
        float vv = acc[i][jq][r] + bias;
        P[(size_t)(rowb + r) * 1024 + col] = f16bits(vv);
      }
    }
  }
}

// ---------------------------------------------------------------------------
// Kernel 2: persistent scan, sliced-partial design (R2 structure).
// 64 blocks x 512 threads; 2 waves/SIMD pinned -> 256 VGPR cap, no spill.
// Lane l: slice s8=l>>3 (32 h-elems), q8=l&7. Group (w,q8) owns 12 z/r/g rows
// (weights in regs) + 4 c rows (Wc streamed from rotated LDS).
// ---------------------------------------------------------------------------
__global__ __attribute__((amdgpu_flat_work_group_size(512, 512),
                          amdgpu_waves_per_eu(2, 2)))
void gru_scan(
    const float* __restrict__ Wz, const float* __restrict__ Wr,
    const float* __restrict__ Wc, const float* __restrict__ Wh,
    const float* __restrict__ gamma, const float* __restrict__ beta,
    const unsigned short* __restrict__ P,
    float* __restrict__ out)
{
  __shared__ __align__(16) unsigned char wc_lds[256 * 512];  // Wc f16, rotated
  __shared__ __align__(16) unsigned char hpad[640];          // h f16: slice s at s*80
  __shared__ __align__(16) unsigned char rhpad[640];         // rh f16 same layout
  __shared__ float pre[768];   // z[0,256) r[256,512) g then c reuse [512,768)
  __shared__ float2 red[4];

  const int t = threadIdx.x;
  const int b = blockIdx.x;
  const int w = t >> 6;
  const int l = t & 63;
  const int s8 = l >> 3;
  const int q8 = l & 7;
  const int j = t & 255;

  // ---- stage Wc -> LDS as f16, rotation-swizzled: off' = (off + (row&31)*16) & 511
  #pragma unroll
  for (int it = 0; it < 16; ++it) {
    int f = it * 512 + t;
    int rho = f >> 5;
    int slot = f & 31;
    const float* src = Wc + rho * 512 + 256 + slot * 8;
    f32x4 v0 = *(const f32x4*)(src);
    f32x4 v1 = *(const f32x4*)(src + 4);
    uint4 pw;
    pw.x = pk16(v0[0], v0[1]); pw.y = pk16(v0[2], v0[3]);
    pw.z = pk16(v1[0], v1[1]); pw.w = pk16(v1[2], v1[3]);
    int off = (slot * 16 + ((rho & 31) << 4)) & 511;
    *(uint4*)(wc_lds + rho * 512 + off) = pw;
  }

  // ---- A-gate weights (z,r,g) in registers: 12 rows x 32 f16 = 192 VGPRs
  unsigned int wA[12][16];
  #pragma unroll
  for (int i = 0; i < 12; ++i) {
    int rho = 96 * w + 8 * i + q8;
    const float* Wp = (rho < 256) ? Wz : (rho < 512) ? Wr : Wh;
    const float* src = Wp + (rho & 255) * 512 + 256 + s8 * 32;
    #pragma unroll
    for (int m = 0; m < 8; ++m) {
      f32x4 v = *(const f32x4*)(src + m * 4);
      wA[i][2 * m]     = pk16(v[0], v[1]);
      wA[i][2 * m + 1] = pk16(v[2], v[3]);
    }
  }

  if (t < 160) { ((unsigned int*)hpad)[t] = 0u; ((unsigned int*)rhpad)[t] = 0u; }

  float h_own = 0.f, gam = 0.f, bet = 0.f;
  if (t < 256) { gam = gamma[j]; bet = beta[j]; }
  unsigned short czx = 0, crx = 0, ccx = 0, cgx = 0;
  if (t < 256) {
    const unsigned short* pb = P + (size_t)b * 1024;
    czx = pb[j]; crx = pb[256 + j]; ccx = pb[512 + j]; cgx = pb[768 + j];
  }
  __syncthreads();

  float zval = 0.f, gval = 0.f;
  #pragma unroll 1
  for (int s = 0; s < S_LEN; ++s) {
    unsigned short nzx = 0, nrx = 0, ncx = 0, ngx = 0;
    if (t < 256 && s + 1 < S_LEN) {
      const unsigned short* pb = P + ((size_t)(s + 1) * 64 + b) * 1024;
      nzx = pb[j]; nrx = pb[256 + j]; ncx = pb[512 + j]; ngx = pb[768 + j];
    }
    // ---- Phase A: z,r,g partial dots over own 32-elem h slice
    unsigned int hh[16];
    #pragma unroll
    for (int u = 0; u < 4; ++u) {
      uint4 hv = *(const uint4*)(hpad + s8 * 80 + u * 16);
      hh[4*u] = hv.x; hh[4*u+1] = hv.y; hh[4*u+2] = hv.z; hh[4*u+3] = hv.w;
    }
    float acc[12];
    #pragma unroll
    for (int i = 0; i < 12; ++i) {
      float a = 0.f;
      #pragma unroll
      for (int v = 0; v < 16; ++v) a = dot2a(hh[v], wA[i][v], a);
      a += __shfl_xor(a, 8);
      a += __shfl_xor(a, 16);
      a += __shfl_xor(a, 32);
      acc[i] = a;
    }
    {
      float v1s = (s8==0)?acc[0]:(s8==1)?acc[1]:(s8==2)?acc[2]:(s8==3)?acc[3]:
                  (s8==4)?acc[4]:(s8==5)?acc[5]:(s8==6)?acc[6]:acc[7];
      pre[96 * w + l] = v1s;
      if (l < 32) {
        int i2 = l >> 3;
        float v2s = (i2==0)?acc[8]:(i2==1)?acc[9]:(i2==2)?acc[10]:acc[11];
        pre[96 * w + 64 + l] = v2s;
      }
    }
    __syncthreads();                                   // (1)
    // ---- Phase B: gates z,r,g; distribute rh
    if (t < 256) {
      zval = sigm(pre[j] + uph(czx));
      float rr = sigm(pre[256 + j] + uph(crx));
      gval = sigm(pre[512 + j] + uph(cgx));
      float rh = rr * h_own;
      *(unsigned short*)(rhpad + (j >> 5) * 80 + (j & 31) * 2) = f16bits(rh);
    }
    __syncthreads();                                   // (2)
    // ---- Phase C: c partial dots, Wc from rotated LDS
    unsigned int rr16[16];
    #pragma unroll
    for (int u = 0; u < 4; ++u) {
      uint4 hv = *(const uint4*)(rhpad + s8 * 80 + u * 16);
      rr16[4*u] = hv.x; rr16[4*u+1] = hv.y; rr16[4*u+2] = hv.z; rr16[4*u+3] = hv.w;
    }
    float accC[4];
    #pragma unroll
    for (int i = 0; i < 4; ++i) {
      int rho = 32 * w + 8 * i + q8;
      const unsigned char* base = wc_lds + rho * 512;
      int r5x = (rho & 31) << 4;
      float a = 0.f;
      #pragma unroll
      for (int u = 0; u < 4; ++u) {
        uint4 wv = *(const uint4*)(base + ((s8 * 64 + u * 16 + r5x) & 511));
        a = dot2a(rr16[4*u+0], wv.x, a);
        a = dot2a(rr16[4*u+1], wv.y, a);
        a = dot2a(rr16[4*u+2], wv.z, a);
        a = dot2a(rr16[4*u+3], wv.w, a);
      }
      a += __shfl_xor(a, 8);
      a += __shfl_xor(a, 16);
      a += __shfl_xor(a, 32);
      accC[i] = a;
    }
    if (l < 32) {
      int i2 = l >> 3;
      float vcs = (i2==0)?accC[0]:(i2==1)?accC[1]:(i2==2)?accC[2]:accC[3];
      pre[512 + 32 * w + l] = vcs;
    }
    __syncthreads();                                   // (3)
    // ---- Phase D: combine + highway + LN
    float hfin = 0.f;
    if (t < 256) {
      float ht = tanh_fast(pre[512 + j] + uph(ccx));
      float hn = (1.f - zval) * h_own + zval * ht;
      hfin = gval * hn + (1.f - gval) * h_own;
      h_own = hn;
      *(unsigned short*)(hpad + (j >> 5) * 80 + (j & 31) * 2) = f16bits(hn);
      float s1 = hfin, s2 = hfin * hfin;
      #pragma unroll
      for (int off = 1; off < 64; off <<= 1) {
        s1 += __shfl_xor(s1, off);
        s2 += __shfl_xor(s2, off);
      }
      if ((t & 63) == 0) red[t >> 6] = make_float2(s1, s2);
    }
    __syncthreads();                                   // (4)
    if (t < 256) {
      float S1 = red[0].x + red[1].x + red[2].x + red[3].x;
      float S2 = red[0].y + red[1].y + red[2].y + red[3].y;
      float mu = S1 * (1.0f / 256.0f);
      float var = S2 * (1.0f / 256.0f) - mu * mu;
      float rs = rsqrtf(var + 1e-5f);
      out[(size_t)s * 16384 + b * 256 + j] = (hfin - mu) * rs * gam + bet;
    }
    czx = nzx; crx = nrx; ccx = ncx; cgx = ngx;
  }
  if (t < 256) out[(size_t)33554432 + b * 256 + j] = h_own;
}

extern "C" void kernel_launch(void* const* d_in, const int* in_sizes, int n_in,
                              void* d_out, int out_size, void* d_ws, size_t ws_size,
                              hipStream_t stream) {
  const float* x  = (const float*)d_in[0];
  const float* Wz = (const float*)d_in[1];
  const float* bz = (const float*)d_in[2];
  const float* Wr = (const float*)d_in[3];
  const float* br = (const float*)d_in[4];
  const float* Wc = (const float*)d_in[5];
  const float* bc = (const float*)d_in[6];
  const float* Wh = (const float*)d_in[7];
  const float* bh = (const float*)d_in[8];
  const float* gamma = (const float*)d_in[9];
  const float* beta  = (const float*)d_in[10];
  unsigned short* P = (unsigned short*)d_ws;   // 131072 x 1024 f16 = 256 MB
  float* out = (float*)d_out;

  dim3 g1(8, 1024);
  gemm_pre<<<g1, 256, 0, stream>>>(x, Wz, bz, Wr, br, Wc, bc, Wh, bh, P);
  gru_scan<<<64, 512, 0, stream>>>(Wz, Wr, Wc, Wh, gamma, beta, P, out);
}

// Round 4
// 5208.146 us; speedup vs baseline: 1.8544x; 1.8527x over previous
//
#include <hip/hip_runtime.h>

typedef _Float16 half2v __attribute__((ext_vector_type(2)));
typedef _Float16 half8v __attribute__((ext_vector_type(8)));
typedef float f32x4 __attribute__((ext_vector_type(4)));

#define S_LEN 2048

static __device__ __forceinline__ unsigned int pk16(float a, float b) {
  half2v h; h[0] = (_Float16)a; h[1] = (_Float16)b;
  return __builtin_bit_cast(unsigned int, h);
}
static __device__ __forceinline__ float uph(unsigned short u) {
  return (float)__builtin_bit_cast(_Float16, u);
}
static __device__ __forceinline__ unsigned short f16bits(float x) {
  return __builtin_bit_cast(unsigned short, (_Float16)x);
}
static __device__ __forceinline__ float dot2a(unsigned int h2, unsigned int w2, float acc) {
  return __builtin_amdgcn_fdot2(__builtin_bit_cast(half2v, h2),
                                __builtin_bit_cast(half2v, w2), acc, false);
}
static __device__ __forceinline__ float sigm(float x) {
  return 1.0f / (1.0f + __expf(-x));
}
static __device__ __forceinline__ float tanh_fast(float x) {
  float e = __expf(2.0f * x);
  return 1.0f - 2.0f / (e + 1.0f);   // safe at +/-inf
}

// ---------------------------------------------------------------------------
// Kernel 1: P[m, g*256+j] = f16( x[m,:] . W{g}_x[j,:] + b{g}[j] )  (unchanged)
// ---------------------------------------------------------------------------
__global__ __launch_bounds__(256, 2) void gemm_pre(
    const float* __restrict__ x,
    const float* __restrict__ Wz, const float* __restrict__ bz,
    const float* __restrict__ Wr, const float* __restrict__ br,
    const float* __restrict__ Wc, const float* __restrict__ bc,
    const float* __restrict__ Wh, const float* __restrict__ bh,
    unsigned short* __restrict__ P)
{
  __shared__ __align__(16) char As[128 * 128];
  __shared__ __align__(16) char Bs[128 * 128];
  const int t = threadIdx.x;
  const int lane = t & 63;
  const int wid = t >> 6;
  const int wm = wid >> 1, wn = wid & 1;
  const int n0 = blockIdx.x * 128;
  const int m0 = blockIdx.y * 128;

  f32x4 acc[4][4];
  #pragma unroll
  for (int i = 0; i < 4; ++i)
    #pragma unroll
    for (int jq = 0; jq < 4; ++jq) acc[i][jq] = f32x4{0.f, 0.f, 0.f, 0.f};

  for (int kk = 0; kk < 4; ++kk) {
    __syncthreads();
    #pragma unroll
    for (int it = 0; it < 8; ++it) {
      int fl = it * 256 + t;
      int row = fl >> 4;
      int c4 = fl & 15;
      f32x4 v = *(const f32x4*)(x + (size_t)(m0 + row) * 256 + kk * 64 + c4 * 4);
      uint2 pw; pw.x = pk16(v[0], v[1]); pw.y = pk16(v[2], v[3]);
      *(uint2*)(As + row * 128 + ((c4 * 8) ^ ((row & 7) << 4))) = pw;

      int n = n0 + row;
      int g = n >> 8; int jc = n & 255;
      const float* W = (g == 0) ? Wz : (g == 1) ? Wr : (g == 2) ? Wc : Wh;
      f32x4 wv = *(const f32x4*)(W + jc * 512 + kk * 64 + c4 * 4);
      uint2 qw; qw.x = pk16(wv[0], wv[1]); qw.y = pk16(wv[2], wv[3]);
      *(uint2*)(Bs + row * 128 + ((c4 * 8) ^ ((row & 7) << 4))) = qw;
    }
    __syncthreads();
    #pragma unroll
    for (int k2 = 0; k2 < 2; ++k2) {
      const int kb = k2 * 64 + (lane >> 4) * 16;
      half8v a[4], bfr[4];
      #pragma unroll
      for (int i = 0; i < 4; ++i) {
        int ar = wm * 64 + i * 16 + (lane & 15);
        a[i] = *(const half8v*)(As + ar * 128 + (kb ^ ((ar & 7) << 4)));
        int br2 = wn * 64 + i * 16 + (lane & 15);
        bfr[i] = *(const half8v*)(Bs + br2 * 128 + (kb ^ ((br2 & 7) << 4)));
      }
      #pragma unroll
      for (int i = 0; i < 4; ++i)
        #pragma unroll
        for (int jq = 0; jq < 4; ++jq)
          acc[i][jq] = __builtin_amdgcn_mfma_f32_16x16x32_f16(a[i], bfr[jq], acc[i][jq], 0, 0, 0);
    }
  }
  #pragma unroll
  for (int jq = 0; jq < 4; ++jq) {
    int col = n0 + wn * 64 + jq * 16 + (lane & 15);
    int g = col >> 8; int jc = col & 255;
    const float* bp = (g == 0) ? bz : (g == 1) ? br : (g == 2) ? bc : bh;
    float bias = bp[jc];
    #pragma unroll
    for (int i = 0; i < 4; ++i) {
      int rowb = m0 + wm * 64 + i * 16 + (lane >> 4) * 4;
      #pragma unroll
      for (int r = 0; r < 4; ++r) {
        float vv = acc[i][jq][r] + bias;
        P[(size_t)(rowb + r) * 1024 + col] = f16bits(vv);
      }
    }
  }
}

// ---------------------------------------------------------------------------
// Kernel 2: sequential scan (z, r, c only — g/LN offloaded).
// 64 blocks x 512 threads, __launch_bounds__(512,1) -> 2 waves/EU -> 256 VGPR.
// Group G=(w*8+q8) owns z/r rows 8G+i (regs, 128 VGPR); Wc in LDS with
// granule-per-lane layout (conflict-free b128). Writes h[s] f16 into P z-slot.
// ---------------------------------------------------------------------------
__global__ __launch_bounds__(512, 1) void gru_scan(
    const float* __restrict__ Wz, const float* __restrict__ Wr,
    const float* __restrict__ Wc,
    unsigned short* P, float* __restrict__ out)
{
  __shared__ __align__(16) unsigned char wc_lds[131072];  // [w][i][u][lane] 16B granules
  __shared__ __align__(16) unsigned char hpad[640];       // h f16, slice s at s*80
  __shared__ __align__(16) unsigned char rhpad[640];      // r*h f16, same layout
  __shared__ float pre[512];    // z rows [0,256), r rows [256,512)
  __shared__ float prec[256];   // c rows

  const int t = threadIdx.x;
  const int b = blockIdx.x;
  const int w = t >> 6;
  const int l = t & 63;
  const int s8 = l >> 3;
  const int q8 = l & 7;
  const int G = w * 8 + q8;
  const int j = t & 255;

  // ---- z/r weights in registers: rows 8G+i, slice s8 (32 f16 = 16 u32 each)
  unsigned int wZR[8][16];
  #pragma unroll
  for (int i = 0; i < 8; ++i) {
    int rho = 8 * G + i;
    const float* src = ((rho < 256) ? (Wz + rho * 512) : (Wr + (rho - 256) * 512))
                       + 256 + s8 * 32;
    #pragma unroll
    for (int m = 0; m < 8; ++m) {
      f32x4 v = *(const f32x4*)(src + m * 4);
      wZR[i][2 * m]     = pk16(v[0], v[1]);
      wZR[i][2 * m + 1] = pk16(v[2], v[3]);
    }
  }

  // ---- stage Wc -> LDS, granule-per-lane layout:
  // granule gi = ((ww*4+ii)*4+u)*64 + lane  holds Wc[4*(8*ww+(lane&7))+ii]
  //   elements [ (lane>>3)*32 + u*8 , +8 )
  #pragma unroll
  for (int it = 0; it < 16; ++it) {
    int gi = it * 512 + t;
    int lane = gi & 63;
    int u  = (gi >> 6) & 3;
    int ii = (gi >> 8) & 3;
    int ww = gi >> 10;
    int row = 4 * (8 * ww + (lane & 7)) + ii;
    const float* src = Wc + row * 512 + 256 + (lane >> 3) * 32 + u * 8;
    f32x4 v0 = *(const f32x4*)(src);
    f32x4 v1 = *(const f32x4*)(src + 4);
    uint4 pw;
    pw.x = pk16(v0[0], v0[1]); pw.y = pk16(v0[2], v0[3]);
    pw.z = pk16(v1[0], v1[1]); pw.w = pk16(v1[2], v1[3]);
    *(uint4*)(wc_lds + gi * 16) = pw;
  }

  if (t < 160) { ((unsigned int*)hpad)[t] = 0u; ((unsigned int*)rhpad)[t] = 0u; }

  float h_own = 0.f;
  unsigned short czx = 0, crx = 0, ccx = 0;
  if (t < 256) {
    const unsigned short* pb = P + (size_t)b * 1024;
    czx = pb[j]; crx = pb[256 + j]; ccx = pb[512 + j];
  }
  __syncthreads();

  float zval = 0.f;
  #pragma unroll 1
  for (int s = 0; s < S_LEN; ++s) {
    unsigned short nzx = 0, nrx = 0, ncx = 0;
    if (t < 256 && s + 1 < S_LEN) {
      const unsigned short* pb = P + ((size_t)(s + 1) * 64 + b) * 1024;
      nzx = pb[j]; nrx = pb[256 + j]; ncx = pb[512 + j];
    }
    // ---- Phase A: z,r partial dots over own 32-elem h slice
    float acc[8];
    #pragma unroll
    for (int i = 0; i < 8; ++i) acc[i] = 0.f;
    #pragma unroll
    for (int u = 0; u < 4; ++u) {
      uint4 hv = *(const uint4*)(hpad + s8 * 80 + u * 16);
      #pragma unroll
      for (int i = 0; i < 8; ++i) {
        acc[i] = dot2a(hv.x, wZR[i][4 * u + 0], acc[i]);
        acc[i] = dot2a(hv.y, wZR[i][4 * u + 1], acc[i]);
        acc[i] = dot2a(hv.z, wZR[i][4 * u + 2], acc[i]);
        acc[i] = dot2a(hv.w, wZR[i][4 * u + 3], acc[i]);
      }
    }
    #pragma unroll
    for (int i = 0; i < 8; ++i) {
      acc[i] += __shfl_xor(acc[i], 8);
      acc[i] += __shfl_xor(acc[i], 16);
      acc[i] += __shfl_xor(acc[i], 32);
    }
    {
      float v1s = (s8==0)?acc[0]:(s8==1)?acc[1]:(s8==2)?acc[2]:(s8==3)?acc[3]:
                  (s8==4)?acc[4]:(s8==5)?acc[5]:(s8==6)?acc[6]:acc[7];
      pre[64 * w + 8 * q8 + s8] = v1s;
    }
    __syncthreads();                                   // (1)
    // ---- Phase B: z, r gates; distribute rh
    if (t < 256) {
      zval = sigm(pre[j] + uph(czx));
      float rr = sigm(pre[256 + j] + uph(crx));
      float rh = rr * h_own;
      *(unsigned short*)(rhpad + (j >> 5) * 80 + (j & 31) * 2) = f16bits(rh);
    }
    __syncthreads();                                   // (2)
    // ---- Phase C: c partial dots, Wc from granule-layout LDS
    float accC[4];
    #pragma unroll
    for (int i = 0; i < 4; ++i) accC[i] = 0.f;
    #pragma unroll
    for (int u = 0; u < 4; ++u) {
      uint4 rv = *(const uint4*)(rhpad + s8 * 80 + u * 16);
      #pragma unroll
      for (int i = 0; i < 4; ++i) {
        uint4 wv = *(const uint4*)(wc_lds + ((((w * 4 + i) * 4 + u) * 64 + l) << 4));
        accC[i] = dot2a(rv.x, wv.x, accC[i]);
        accC[i] = dot2a(rv.y, wv.y, accC[i]);
        accC[i] = dot2a(rv.z, wv.z, accC[i]);
        accC[i] = dot2a(rv.w, wv.w, accC[i]);
      }
    }
    #pragma unroll
    for (int i = 0; i < 4; ++i) {
      accC[i] += __shfl_xor(accC[i], 8);
      accC[i] += __shfl_xor(accC[i], 16);
      accC[i] += __shfl_xor(accC[i], 32);
    }
    if (s8 < 4) {
      float vcs = (s8==0)?accC[0]:(s8==1)?accC[1]:(s8==2)?accC[2]:accC[3];
      prec[32 * w + 4 * q8 + s8] = vcs;
    }
    __syncthreads();                                   // (3)
    // ---- Phase D: combine; write h to LDS + global (P z-slot)
    if (t < 256) {
      float ht = tanh_fast(prec[j] + uph(ccx));
      float hn = (1.f - zval) * h_own + zval * ht;
      h_own = hn;
      unsigned short hb = f16bits(hn);
      *(unsigned short*)(hpad + (j >> 5) * 80 + (j & 31) * 2) = hb;
      P[(size_t)(s * 64 + b) * 1024 + j] = hb;
    }
    czx = nzx; crx = nrx; ccx = ncx;
    __syncthreads();                                   // (4)
  }
  if (t < 256) out[(size_t)33554432 + b * 256 + j] = h_own;
}

// ---------------------------------------------------------------------------
// Kernel 3: g-gate + highway + LayerNorm, fully parallel over s.
// 2048 blocks (one per s) x 256 threads (one per output j).
// Thread j holds Wg row j (128 VGPRs); h_prev rows staged in LDS (broadcast).
// ---------------------------------------------------------------------------
__global__ __launch_bounds__(256, 1) void g_hwy_ln(
    const float* __restrict__ Wh,
    const float* __restrict__ gamma, const float* __restrict__ beta,
    const unsigned short* __restrict__ P,
    float* __restrict__ out)
{
  __shared__ __align__(16) unsigned int hp_lds[8192];  // 64 rows x 256 f16 = 32 KB
  __shared__ float red1[4], red2[4];

  const int s = blockIdx.x;
  const int j = threadIdx.x;
  const int w = j >> 6;

  unsigned int wg[128];
  {
    const float* src = Wh + j * 512 + 256;
    #pragma unroll
    for (int m = 0; m < 64; ++m) {
      f32x4 v = *(const f32x4*)(src + m * 4);
      wg[2 * m]     = pk16(v[0], v[1]);
      wg[2 * m + 1] = pk16(v[2], v[3]);
    }
  }
  float gam = gamma[j], bet = beta[j];

  if (s == 0) {
    #pragma unroll
    for (int it = 0; it < 8; ++it) {
      uint4 z4 = uint4{0u, 0u, 0u, 0u};
      *(uint4*)((char*)hp_lds + (it * 256 + j) * 16) = z4;
    }
  } else {
    #pragma unroll
    for (int it = 0; it < 8; ++it) {
      int gi = it * 256 + j;
      int bb = gi >> 5;
      int g32 = gi & 31;
      uint4 v = *(const uint4*)(P + ((size_t)(s - 1) * 64 + bb) * 1024 + g32 * 8);
      *(uint4*)((char*)hp_lds + gi * 16) = v;
    }
  }
  __syncthreads();

  #pragma unroll 1
  for (int b = 0; b < 64; ++b) {
    const unsigned int* hp = hp_lds + b * 128;
    float a0 = 0.f, a1 = 0.f;
    #pragma unroll
    for (int k = 0; k < 32; ++k) {
      uint4 hv = *(const uint4*)(hp + k * 4);
      a0 = dot2a(hv.x, wg[4 * k + 0], a0);
      a1 = dot2a(hv.y, wg[4 * k + 1], a1);
      a0 = dot2a(hv.z, wg[4 * k + 2], a0);
      a1 = dot2a(hv.w, wg[4 * k + 3], a1);
    }
    float dot = a0 + a1;
    const unsigned short* prow = P + ((size_t)s * 64 + b) * 1024;
    float gx = uph(prow[768 + j]);
    float hnew = uph(prow[j]);
    float hpj = uph(((const unsigned short*)hp_lds)[b * 256 + j]);
    float g = sigm(gx + dot);
    float hf = g * hnew + (1.f - g) * hpj;
    // LayerNorm over 256 threads
    float s1 = hf, s2 = hf * hf;
    #pragma unroll
    for (int off = 1; off < 64; off <<= 1) {
      s1 += __shfl_xor(s1, off);
      s2 += __shfl_xor(s2, off);
    }
    if ((j & 63) == 0) { red1[w] = s1; red2[w] = s2; }
    __syncthreads();
    float S1 = red1[0] + red1[1] + red1[2] + red1[3];
    float S2 = red2[0] + red2[1] + red2[2] + red2[3];
    float mu = S1 * (1.0f / 256.0f);
    float var = S2 * (1.0f / 256.0f) - mu * mu;
    float rs = rsqrtf(var + 1e-5f);
    out[((size_t)s * 64 + b) * 256 + j] = (hf - mu) * rs * gam + bet;
    __syncthreads();
  }
}

extern "C" void kernel_launch(void* const* d_in, const int* in_sizes, int n_in,
                              void* d_out, int out_size, void* d_ws, size_t ws_size,
                              hipStream_t stream) {
  const float* x  = (const float*)d_in[0];
  const float* Wz = (const float*)d_in[1];
  const float* bz = (const float*)d_in[2];
  const float* Wr = (const float*)d_in[3];
  const float* br = (const float*)d_in[4];
  const float* Wc = (const float*)d_in[5];
  const float* bc = (const float*)d_in[6];
  const float* Wh = (const float*)d_in[7];
  const float* bh = (const float*)d_in[8];
  const float* gamma = (const float*)d_in[9];
  const float* beta  = (const float*)d_in[10];
  unsigned short* P = (unsigned short*)d_ws;   // 131072 x 1024 f16 = 256 MB
  float* out = (float*)d_out;

  dim3 g1(8, 1024);
  gemm_pre<<<g1, 256, 0, stream>>>(x, Wz, bz, Wr, br, Wc, bc, Wh, bh, P);
  gru_scan<<<64, 512, 0, stream>>>(Wz, Wr, Wc, P, out);
  g_hwy_ln<<<2048, 256, 0, stream>>>(Wh, gamma, beta, P, out);
}

// Round 5
// 3472.414 us; speedup vs baseline: 2.7814x; 1.4999x over previous
//
#include <hip/hip_runtime.h>

typedef _Float16 half2v __attribute__((ext_vector_type(2)));
typedef _Float16 half8v __attribute__((ext_vector_type(8)));
typedef float f32x4 __attribute__((ext_vector_type(4)));

#define S_LEN 2048

static __device__ __forceinline__ unsigned int pk16(float a, float b) {
  half2v h; h[0] = (_Float16)a; h[1] = (_Float16)b;
  return __builtin_bit_cast(unsigned int, h);
}
static __device__ __forceinline__ float uph(unsigned short u) {
  return (float)__builtin_bit_cast(_Float16, u);
}
static __device__ __forceinline__ unsigned short f16bits(float x) {
  return __builtin_bit_cast(unsigned short, (_Float16)x);
}
static __device__ __forceinline__ float dot2a(unsigned int h2, unsigned int w2, float acc) {
  return __builtin_amdgcn_fdot2(__builtin_bit_cast(half2v, h2),
                                __builtin_bit_cast(half2v, w2), acc, false);
}
static __device__ __forceinline__ float sigm(float x) {
  return 1.0f / (1.0f + __expf(-x));
}
static __device__ __forceinline__ float tanh_fast(float x) {
  float e = __expf(2.0f * x);
  return 1.0f - 2.0f / (e + 1.0f);   // safe at +/-inf
}

// ---------------------------------------------------------------------------
// Kernel 1: P[m, g*256+j] = f16( x[m,:] . W{g}_x[j,:] + b{g}[j] )  (unchanged)
// ---------------------------------------------------------------------------
__global__ __launch_bounds__(256, 2) void gemm_pre(
    const float* __restrict__ x,
    const float* __restrict__ Wz, const float* __restrict__ bz,
    const float* __restrict__ Wr, const float* __restrict__ br,
    const float* __restrict__ Wc, const float* __restrict__ bc,
    const float* __restrict__ Wh, const float* __restrict__ bh,
    unsigned short* __restrict__ P)
{
  __shared__ __align__(16) char As[128 * 128];
  __shared__ __align__(16) char Bs[128 * 128];
  const int t = threadIdx.x;
  const int lane = t & 63;
  const int wid = t >> 6;
  const int wm = wid >> 1, wn = wid & 1;
  const int n0 = blockIdx.x * 128;
  const int m0 = blockIdx.y * 128;

  f32x4 acc[4][4];
  #pragma unroll
  for (int i = 0; i < 4; ++i)
    #pragma unroll
    for (int jq = 0; jq < 4; ++jq) acc[i][jq] = f32x4{0.f, 0.f, 0.f, 0.f};

  for (int kk = 0; kk < 4; ++kk) {
    __syncthreads();
    #pragma unroll
    for (int it = 0; it < 8; ++it) {
      int fl = it * 256 + t;
      int row = fl >> 4;
      int c4 = fl & 15;
      f32x4 v = *(const f32x4*)(x + (size_t)(m0 + row) * 256 + kk * 64 + c4 * 4);
      uint2 pw; pw.x = pk16(v[0], v[1]); pw.y = pk16(v[2], v[3]);
      *(uint2*)(As + row * 128 + ((c4 * 8) ^ ((row & 7) << 4))) = pw;

      int n = n0 + row;
      int g = n >> 8; int jc = n & 255;
      const float* W = (g == 0) ? Wz : (g == 1) ? Wr : (g == 2) ? Wc : Wh;
      f32x4 wv = *(const f32x4*)(W + jc * 512 + kk * 64 + c4 * 4);
      uint2 qw; qw.x = pk16(wv[0], wv[1]); qw.y = pk16(wv[2], wv[3]);
      *(uint2*)(Bs + row * 128 + ((c4 * 8) ^ ((row & 7) << 4))) = qw;
    }
    __syncthreads();
    #pragma unroll
    for (int k2 = 0; k2 < 2; ++k2) {
      const int kb = k2 * 64 + (lane >> 4) * 16;
      half8v a[4], bfr[4];
      #pragma unroll
      for (int i = 0; i < 4; ++i) {
        int ar = wm * 64 + i * 16 + (lane & 15);
        a[i] = *(const half8v*)(As + ar * 128 + (kb ^ ((ar & 7) << 4)));
        int br2 = wn * 64 + i * 16 + (lane & 15);
        bfr[i] = *(const half8v*)(Bs + br2 * 128 + (kb ^ ((br2 & 7) << 4)));
      }
      #pragma unroll
      for (int i = 0; i < 4; ++i)
        #pragma unroll
        for (int jq = 0; jq < 4; ++jq)
          acc[i][jq] = __builtin_amdgcn_mfma_f32_16x16x32_f16(a[i], bfr[jq], acc[i][jq], 0, 0, 0);
    }
  }
  #pragma unroll
  for (int jq = 0; jq < 4; ++jq) {
    int col = n0 + wn * 64 + jq * 16 + (lane & 15);
    int g = col >> 8; int jc = col & 255;
    const float* bp = (g == 0) ? bz : (g == 1) ? br : (g == 2) ? bc : bh;
    float bias = bp[jc];
    #pragma unroll
    for (int i = 0; i < 4; ++i) {
      int rowb = m0 + wm * 64 + i * 16 + (lane >> 4) * 4;
      #pragma unroll
      for (int r = 0; r < 4; ++r) {
        float vv = acc[i][jq][r] + bias;
        P[(size_t)(rowb + r) * 1024 + col] = f16bits(vv);
      }
    }
  }
}

// ---------------------------------------------------------------------------
// Kernel 2: sequential scan (z, r, c). 64 blocks x 512 threads.
// 4-way slicing: lane l = (q = l&15, s4 = l>>4); group G = w*16+q owns
// z/r rows 4G+i (i=0..3) and c rows 2G+ii (ii=0..1), slice [s4*64, +64).
// ALL weights in registers (192 u32/thread). h/rh in 160B-pitch LDS slices.
// 3 barriers/step. Writes h[s] f16 into P z-slot for kernel 3.
// ---------------------------------------------------------------------------
__global__ __launch_bounds__(512, 1) void gru_scan(
    const float* __restrict__ Wz, const float* __restrict__ Wr,
    const float* __restrict__ Wc,
    unsigned short* P, float* __restrict__ out)
{
  __shared__ __align__(16) unsigned char hpad[4 * 160];   // h f16, slice s4 at s4*160
  __shared__ __align__(16) unsigned char rhpad[4 * 160];  // r*h f16, same layout
  __shared__ float pre[256];    // z preacts (raw)
  __shared__ float prec[256];   // c preacts (raw)

  const int t = threadIdx.x;
  const int b = blockIdx.x;
  const int w = t >> 6;
  const int l = t & 63;
  const int q = l & 15;
  const int s4 = l >> 4;
  const int G = w * 16 + q;           // 0..127
  const int j = t & 255;
  const int j2c = 4 * (G - 64) + s4;  // r-row index for w>=4 lanes

  // ---- z/r weights: rows 4G+i, slice s4 (64 f16 = 32 u32 each)
  unsigned int wZR[4][32];
  #pragma unroll
  for (int i = 0; i < 4; ++i) {
    int row = 4 * G + i;
    const float* src = ((row < 256) ? (Wz + row * 512)
                                    : (Wr + (row - 256) * 512)) + 256 + s4 * 64;
    #pragma unroll
    for (int m = 0; m < 16; ++m) {
      f32x4 v = *(const f32x4*)(src + m * 4);
      wZR[i][2 * m]     = pk16(v[0], v[1]);
      wZR[i][2 * m + 1] = pk16(v[2], v[3]);
    }
  }
  // ---- c weights: rows 2G+ii, slice s4
  unsigned int wC[2][32];
  #pragma unroll
  for (int ii = 0; ii < 2; ++ii) {
    int row = 2 * G + ii;
    const float* src = Wc + row * 512 + 256 + s4 * 64;
    #pragma unroll
    for (int m = 0; m < 16; ++m) {
      f32x4 v = *(const f32x4*)(src + m * 4);
      wC[ii][2 * m]     = pk16(v[0], v[1]);
      wC[ii][2 * m + 1] = pk16(v[2], v[3]);
    }
  }

  if (t < 160) ((unsigned int*)hpad)[t] = 0u;

  float h_own = 0.f;
  unsigned short czx = 0, crx = 0, ccx = 0;
  {
    const unsigned short* pb = P + b * 1024;
    if (w < 4) { czx = pb[j]; ccx = pb[512 + j]; }
    else       { crx = pb[256 + j2c]; }
  }
  int pnext = b * 1024 + 65536;   // P row offset for step s+1
  int pcur  = b * 1024;           // P row offset for step s (h store)
  __syncthreads();

  #pragma unroll 1
  for (int s = 0; s < S_LEN; ++s) {
    unsigned short nzx = 0, nrx = 0, ncx = 0;
    if (s + 1 < S_LEN) {
      if (w < 4) { nzx = P[pnext + j]; ncx = P[pnext + 512 + j]; }
      else       { nrx = P[pnext + 256 + j2c]; }
    }
    // ---- Phase A: z/r dots over own 64-elem slice of h
    float a0 = 0.f, a1 = 0.f, a2 = 0.f, a3 = 0.f;
    {
      const uint4* hb = (const uint4*)(hpad + s4 * 160);
      #pragma unroll
      for (int u = 0; u < 8; ++u) {
        uint4 hv = hb[u];
        a0 = dot2a(hv.x, wZR[0][4*u+0], a0);
        a0 = dot2a(hv.y, wZR[0][4*u+1], a0);
        a0 = dot2a(hv.z, wZR[0][4*u+2], a0);
        a0 = dot2a(hv.w, wZR[0][4*u+3], a0);
        a1 = dot2a(hv.x, wZR[1][4*u+0], a1);
        a1 = dot2a(hv.y, wZR[1][4*u+1], a1);
        a1 = dot2a(hv.z, wZR[1][4*u+2], a1);
        a1 = dot2a(hv.w, wZR[1][4*u+3], a1);
        a2 = dot2a(hv.x, wZR[2][4*u+0], a2);
        a2 = dot2a(hv.y, wZR[2][4*u+1], a2);
        a2 = dot2a(hv.z, wZR[2][4*u+2], a2);
        a2 = dot2a(hv.w, wZR[2][4*u+3], a2);
        a3 = dot2a(hv.x, wZR[3][4*u+0], a3);
        a3 = dot2a(hv.y, wZR[3][4*u+1], a3);
        a3 = dot2a(hv.z, wZR[3][4*u+2], a3);
        a3 = dot2a(hv.w, wZR[3][4*u+3], a3);
      }
    }
    a0 += __shfl_xor(a0, 16); a0 += __shfl_xor(a0, 32);
    a1 += __shfl_xor(a1, 16); a1 += __shfl_xor(a1, 32);
    a2 += __shfl_xor(a2, 16); a2 += __shfl_xor(a2, 32);
    a3 += __shfl_xor(a3, 16); a3 += __shfl_xor(a3, 32);
    {
      float av = (s4 == 0) ? a0 : (s4 == 1) ? a1 : (s4 == 2) ? a2 : a3;
      int rowA = 4 * G + s4;
      if (rowA < 256) {
        pre[rowA] = av;
      } else {
        int j2 = rowA - 256;
        float rr = sigm(av + uph(crx));
        float hj = uph(*(const unsigned short*)(hpad + (j2 >> 6) * 160 + (j2 & 63) * 2));
        *(unsigned short*)(rhpad + (j2 >> 6) * 160 + (j2 & 63) * 2) = f16bits(rr * hj);
      }
    }
    __syncthreads();                                   // (1) rhpad, pre ready
    // ---- Phase C: c dots over own 64-elem slice of rh
    float c0 = 0.f, c1 = 0.f;
    {
      const uint4* rb = (const uint4*)(rhpad + s4 * 160);
      #pragma unroll
      for (int u = 0; u < 8; ++u) {
        uint4 rv = rb[u];
        c0 = dot2a(rv.x, wC[0][4*u+0], c0);
        c0 = dot2a(rv.y, wC[0][4*u+1], c0);
        c0 = dot2a(rv.z, wC[0][4*u+2], c0);
        c0 = dot2a(rv.w, wC[0][4*u+3], c0);
        c1 = dot2a(rv.x, wC[1][4*u+0], c1);
        c1 = dot2a(rv.y, wC[1][4*u+1], c1);
        c1 = dot2a(rv.z, wC[1][4*u+2], c1);
        c1 = dot2a(rv.w, wC[1][4*u+3], c1);
      }
    }
    c0 += __shfl_xor(c0, 16); c0 += __shfl_xor(c0, 32);
    c1 += __shfl_xor(c1, 16); c1 += __shfl_xor(c1, 32);
    if (s4 < 2) prec[2 * G + s4] = (s4 == 0) ? c0 : c1;
    __syncthreads();                                   // (2) prec ready
    // ---- Phase D: combine; publish h
    if (t < 256) {
      float z  = sigm(pre[j] + uph(czx));
      float ht = tanh_fast(prec[j] + uph(ccx));
      float hn = (1.f - z) * h_own + z * ht;
      h_own = hn;
      unsigned short hb16 = f16bits(hn);
      *(unsigned short*)(hpad + (j >> 6) * 160 + (j & 63) * 2) = hb16;
      P[pcur + j] = hb16;
    }
    czx = nzx; crx = nrx; ccx = ncx;
    pcur += 65536; pnext += 65536;
    __syncthreads();                                   // (3) hpad ready
  }
  if (t < 256) out[(size_t)33554432 + b * 256 + j] = h_own;
}

// ---------------------------------------------------------------------------
// Kernel 3: g-gate + highway + LayerNorm as MFMA GEMM.
// out_hf[m, :] = LN( g*hnew + (1-g)*hprev ),  g = sigmoid(gx + hprev.Wg^T).
// A = hprev (h shifted by one step, f16 from P z-slot), B = Wg_h.
// 1024 blocks x 512 thr; BM=128, BN=256 (full row -> block-local LN), BK=64.
// ---------------------------------------------------------------------------
__global__ __launch_bounds__(512, 2) void g_mfma_ln(
    const float* __restrict__ Wh,
    const float* __restrict__ gamma, const float* __restrict__ beta,
    const unsigned short* __restrict__ P,
    float* __restrict__ out)
{
  __shared__ __align__(16) char As[128 * 128];    // hprev tile f16 (swizzled)
  __shared__ __align__(16) char Bs[256 * 128];    // Wg tile f16 (swizzled)
  __shared__ float red1[128][4];
  __shared__ float red2[128][4];
  __shared__ float2 murs[128];

  const int t = threadIdx.x;
  const int lane = t & 63;
  const int wid = t >> 6;
  const int wm = wid >> 2, wn = wid & 3;          // 2 x 4 wave grid
  const unsigned m0 = blockIdx.x * 128;

  float gam4[4], bet4[4];
  #pragma unroll
  for (int jq = 0; jq < 4; ++jq) {
    int col = wn * 64 + jq * 16 + (lane & 15);
    gam4[jq] = gamma[col];
    bet4[jq] = beta[col];
  }

  f32x4 acc[4][4];
  #pragma unroll
  for (int i = 0; i < 4; ++i)
    #pragma unroll
    for (int jq = 0; jq < 4; ++jq) acc[i][jq] = f32x4{0.f, 0.f, 0.f, 0.f};

  for (int kk = 0; kk < 4; ++kk) {
    __syncthreads();
    // stage A (hprev f16 direct copy): 1024 x 16B granules
    #pragma unroll
    for (int it = 0; it < 2; ++it) {
      int g = it * 512 + t;
      int row = g >> 3;
      int c8 = g & 7;
      int msrc = (int)m0 + row - 64;
      uint4 v = uint4{0u, 0u, 0u, 0u};
      if (msrc >= 0) v = *(const uint4*)(P + (unsigned)msrc * 1024 + kk * 64 + c8 * 8);
      *(uint4*)(As + row * 128 + ((c8 * 16) ^ ((row & 7) << 4))) = v;
    }
    // stage B (Wg f32 -> f16): 2048 x 16B granules
    #pragma unroll
    for (int it = 0; it < 4; ++it) {
      int g = it * 512 + t;
      int row = g >> 3;
      int c8 = g & 7;
      const float* src = Wh + row * 512 + 256 + kk * 64 + c8 * 8;
      f32x4 v0 = *(const f32x4*)(src);
      f32x4 v1 = *(const f32x4*)(src + 4);
      uint4 pw;
      pw.x = pk16(v0[0], v0[1]); pw.y = pk16(v0[2], v0[3]);
      pw.z = pk16(v1[0], v1[1]); pw.w = pk16(v1[2], v1[3]);
      *(uint4*)(Bs + row * 128 + ((c8 * 16) ^ ((row & 7) << 4))) = pw;
    }
    __syncthreads();
    #pragma unroll
    for (int k2 = 0; k2 < 2; ++k2) {
      const int kb = k2 * 64 + (lane >> 4) * 16;
      half8v a[4], bfr[4];
      #pragma unroll
      for (int i = 0; i < 4; ++i) {
        int ar = wm * 64 + i * 16 + (lane & 15);
        a[i] = *(const half8v*)(As + ar * 128 + (kb ^ ((ar & 7) << 4)));
        int br2 = wn * 64 + i * 16 + (lane & 15);
        bfr[i] = *(const half8v*)(Bs + br2 * 128 + (kb ^ ((br2 & 7) << 4)));
      }
      #pragma unroll
      for (int i = 0; i < 4; ++i)
        #pragma unroll
        for (int jq = 0; jq < 4; ++jq)
          acc[i][jq] = __builtin_amdgcn_mfma_f32_16x16x32_f16(a[i], bfr[jq], acc[i][jq], 0, 0, 0);
    }
  }

  // ---- epilogue: g, highway (hf stored back into acc)
  #pragma unroll
  for (int i = 0; i < 4; ++i) {
    #pragma unroll
    for (int r = 0; r < 4; ++r) {
      unsigned mm = m0 + wm * 64 + i * 16 + ((lane >> 4) << 2) + r;
      unsigned bse = mm << 10;
      unsigned bsp = (mm - 64) << 10;
      #pragma unroll
      for (int jq = 0; jq < 4; ++jq) {
        int col = wn * 64 + jq * 16 + (lane & 15);
        float gx = uph(P[bse + 768 + col]);
        float hnew = uph(P[bse + col]);
        float hp = (mm >= 64) ? uph(P[bsp + col]) : 0.f;
        float g = sigm(acc[i][jq][r] + gx);
        acc[i][jq][r] = g * hnew + (1.f - g) * hp;
      }
    }
  }
  // ---- LayerNorm partials (row-local): reduce over 4 jq + 16 col-lanes
  #pragma unroll
  for (int i = 0; i < 4; ++i) {
    #pragma unroll
    for (int r = 0; r < 4; ++r) {
      float s1 = acc[i][0][r] + acc[i][1][r] + acc[i][2][r] + acc[i][3][r];
      float s2 = acc[i][0][r]*acc[i][0][r] + acc[i][1][r]*acc[i][1][r]
               + acc[i][2][r]*acc[i][2][r] + acc[i][3][r]*acc[i][3][r];
      s1 += __shfl_xor(s1, 1); s2 += __shfl_xor(s2, 1);
      s1 += __shfl_xor(s1, 2); s2 += __shfl_xor(s2, 2);
      s1 += __shfl_xor(s1, 4); s2 += __shfl_xor(s2, 4);
      s1 += __shfl_xor(s1, 8); s2 += __shfl_xor(s2, 8);
      if ((lane & 15) == 0) {
        int rowl = wm * 64 + i * 16 + ((lane >> 4) << 2) + r;
        red1[rowl][wn] = s1;
        red2[rowl][wn] = s2;
      }
    }
  }
  __syncthreads();
  if (t < 128) {
    float S1 = red1[t][0] + red1[t][1] + red1[t][2] + red1[t][3];
    float S2 = red2[t][0] + red2[t][1] + red2[t][2] + red2[t][3];
    float mu = S1 * (1.0f / 256.0f);
    float var = S2 * (1.0f / 256.0f) - mu * mu;
    murs[t] = make_float2(mu, rsqrtf(var + 1e-5f));
  }
  __syncthreads();
  #pragma unroll
  for (int i = 0; i < 4; ++i) {
    #pragma unroll
    for (int r = 0; r < 4; ++r) {
      int rowl = wm * 64 + i * 16 + ((lane >> 4) << 2) + r;
      float2 mr = murs[rowl];
      unsigned mm = m0 + rowl;
      #pragma unroll
      for (int jq = 0; jq < 4; ++jq) {
        int col = wn * 64 + jq * 16 + (lane & 15);
        out[(size_t)mm * 256 + col] = (acc[i][jq][r] - mr.x) * mr.y * gam4[jq] + bet4[jq];
      }
    }
  }
}

extern "C" void kernel_launch(void* const* d_in, const int* in_sizes, int n_in,
                              void* d_out, int out_size, void* d_ws, size_t ws_size,
                              hipStream_t stream) {
  const float* x  = (const float*)d_in[0];
  const float* Wz = (const float*)d_in[1];
  const float* bz = (const float*)d_in[2];
  const float* Wr = (const float*)d_in[3];
  const float* br = (const float*)d_in[4];
  const float* Wc = (const float*)d_in[5];
  const float* bc = (const float*)d_in[6];
  const float* Wh = (const float*)d_in[7];
  const float* bh = (const float*)d_in[8];
  const float* gamma = (const float*)d_in[9];
  const float* beta  = (const float*)d_in[10];
  unsigned short* P = (unsigned short*)d_ws;   // 131072 x 1024 f16 = 256 MB
  float* out = (float*)d_out;

  dim3 g1(8, 1024);
  gemm_pre<<<g1, 256, 0, stream>>>(x, Wz, bz, Wr, br, Wc, bc, Wh, bh, P);
  gru_scan<<<64, 512, 0, stream>>>(Wz, Wr, Wc, P, out);
  g_mfma_ln<<<1024, 512, 0, stream>>>(Wh, gamma, beta, P, out);
}